// Round 1
// baseline (37.465 us; speedup 1.0000x reference)
//
#include <hip/hip_runtime.h>

#define BATCH    512
#define L_TOT    569
#define NALLELE  16
#define SEG_LEN  59
#define D_MODEL  256
#define K_CAND   8
#define VOCAB    30
#define COMMON   25
#define NEG_FILL -1000.0f

__global__ __launch_bounds__(256) void mhc_pool_kernel(
    const int*   __restrict__ x,      // (512, 569) tokens
    const float* __restrict__ emb,    // (30, 256)
    const float* __restrict__ wpool,  // (8, 59)
    const float* __restrict__ wpred,  // (256,)
    const float* __restrict__ bpred,  // (1,)
    float*       __restrict__ out)    // (512, 32)
{
    __shared__ float s_edot[VOCAB];
    __shared__ float s_pedot[SEG_LEN];
    __shared__ float s_wpool[K_CAND][SEG_LEN];

    const int tid  = threadIdx.x;
    const int wave = tid >> 6;
    const int lane = tid & 63;

    // ---- Precompute tables: 89 dot products of length 256, wave-parallel.
    // e_dot[v]  = <emb[v,:], W_pred>           (v = 0..29)
    // pe_dot[l] = <PE[l,:],  W_pred>           (l = 0..58)
    const float c0 = -logf(10000.0f) / (float)D_MODEL;
    for (int j = wave; j < VOCAB + SEG_LEN; j += 4) {
        float part = 0.0f;
        #pragma unroll
        for (int q = 0; q < 4; ++q) {
            const int d = lane * 4 + q;          // 0..255
            const float w = wpred[d];
            float v;
            if (j < VOCAB) {
                v = emb[j * D_MODEL + d];
            } else {
                const float pos = (float)(j - VOCAB);
                const float dv  = expf((float)((d >> 1) * 2) * c0);
                const float ang = pos * dv;
                v = (d & 1) ? cosf(ang) : sinf(ang);
            }
            part = fmaf(v, w, part);
        }
        #pragma unroll
        for (int off = 32; off; off >>= 1) part += __shfl_xor(part, off);
        if (lane == 0) {
            if (j < VOCAB) s_edot[j] = part;
            else           s_pedot[j - VOCAB] = part;
        }
    }
    for (int t = tid; t < K_CAND * SEG_LEN; t += 256)
        s_wpool[t / SEG_LEN][t % SEG_LEN] = wpool[t];
    __syncthreads();

    // ---- One thread per (batch b, allele i) pair; allele fastest for
    // broadcast-friendly common-token reads and coalesced output writes.
    const float bp = *bpred;
    const int g = blockIdx.x * 256 + tid;        // 0..8191
    const int i = g & (NALLELE - 1);
    const int b = g >> 4;

    float acc[K_CAND];
    #pragma unroll
    for (int k = 0; k < K_CAND; ++k) acc[k] = bp;

    const int rowbase = b * L_TOT;
    // common segment: l = 0..24 (same tokens across the 16 alleles -> broadcast)
    for (int l = 0; l < COMMON; ++l) {
        const int tok = x[rowbase + l];
        const float s = (tok != 0) ? (s_edot[tok] + s_pedot[l]) : 0.0f;
        #pragma unroll
        for (int k = 0; k < K_CAND; ++k)
            acc[k] = fmaf(s_wpool[k][l], s, acc[k]);
    }
    // allele-specific segment: 34 tokens at x[b, 25 + 34*i ..]
    const int mbase = rowbase + COMMON + 34 * i;
    const int tok0 = x[mbase];
    for (int j = 0; j < 34; ++j) {
        const int tok = x[mbase + j];
        const int l = COMMON + j;
        const float s = (tok != 0) ? (s_edot[tok] + s_pedot[l]) : 0.0f;
        #pragma unroll
        for (int k = 0; k < K_CAND; ++k)
            acc[k] = fmaf(s_wpool[k][l], s, acc[k]);
    }

    // max / argmax over K (first occurrence wins ties, matching jnp.argmax)
    float m = acc[0]; int arg = 0;
    #pragma unroll
    for (int k = 1; k < K_CAND; ++k)
        if (acc[k] > m) { m = acc[k]; arg = k; }

    const bool presence = (tok0 != 0);
    out[b * 32 + i]           = presence ? m          : NEG_FILL;
    out[b * 32 + NALLELE + i] = presence ? (float)arg : -1.0f;
}

extern "C" void kernel_launch(void* const* d_in, const int* in_sizes, int n_in,
                              void* d_out, int out_size, void* d_ws, size_t ws_size,
                              hipStream_t stream) {
    const int*   x     = (const int*)  d_in[0];
    const float* emb   = (const float*)d_in[1];
    const float* wpool = (const float*)d_in[2];
    const float* wpred = (const float*)d_in[3];
    const float* bpred = (const float*)d_in[4];
    float*       out   = (float*)d_out;

    const int total = BATCH * NALLELE;           // 8192 threads
    mhc_pool_kernel<<<total / 256, 256, 0, stream>>>(x, emb, wpool, wpred, bpred, out);
}

// Round 2
// 17.914 us; speedup vs baseline: 2.0914x; 2.0914x over previous
//
#include <hip/hip_runtime.h>

#define BATCH    512
#define L_TOT    569
#define NALLELE  16
#define SEG_LEN  59
#define D_MODEL  256
#define K_CAND   8
#define VOCAB    30
#define COMMON   25
#define NEG_FILL -1000.0f
#define WAVES    4      // waves per block
#define NPAIR    4      // (b,allele) pairs per wave

__global__ __launch_bounds__(256) void mhc_pool_kernel(
    const int*   __restrict__ x,      // (512, 569)
    const float* __restrict__ emb,    // (30, 256)
    const float* __restrict__ wpool,  // (8, 59)
    const float* __restrict__ wpred,  // (256,)
    const float* __restrict__ bpred,  // (1,)
    float*       __restrict__ out)    // (512, 32)
{
    __shared__ float s_edot[VOCAB];
    __shared__ float s_pedot[SEG_LEN];
    __shared__ float s_wpool[K_CAND][SEG_LEN];

    const int tid  = threadIdx.x;
    const int wv   = tid >> 6;
    const int lane = tid & 63;

    // ---- wpool -> LDS
    for (int t = tid; t < K_CAND * SEG_LEN; t += 256)
        s_wpool[t / SEG_LEN][t % SEG_LEN] = wpool[t];

    // ---- tables: e_dot[v] = <emb[v,:],wpred>, pe_dot[l] = <PE[l,:],wpred>
    // Native trig only (no libm slow paths -> no spills). Frequencies hoisted.
    {
        const int    d0  = lane * 4;
        const float4 w4  = *reinterpret_cast<const float4*>(wpred + d0);
        const float  c0  = -9.210340371976184f / (float)D_MODEL;  // -ln(10000)/256
        const float  dv0 = __expf(c0 * (float)(d0));              // even dims d0, d0+1
        const float  dv2 = __expf(c0 * (float)(d0 + 2));          // dims d0+2, d0+3
        for (int j = wv; j < VOCAB + SEG_LEN; j += WAVES) {       // j wave-uniform
            float part;
            if (j < VOCAB) {
                const float4 e4 = *reinterpret_cast<const float4*>(emb + j * D_MODEL + d0);
                part = e4.x * w4.x + e4.y * w4.y + e4.z * w4.z + e4.w * w4.w;
            } else {
                const float pos = (float)(j - VOCAB);
                const float a0 = pos * dv0, a2 = pos * dv2;
                part = __sinf(a0) * w4.x + __cosf(a0) * w4.y
                     + __sinf(a2) * w4.z + __cosf(a2) * w4.w;
            }
            #pragma unroll
            for (int off = 32; off; off >>= 1) part += __shfl_xor(part, off);
            if (lane == 0) {
                if (j < VOCAB) s_edot[j] = part;
                else           s_pedot[j - VOCAB] = part;
            }
        }
    }
    __syncthreads();

    // ---- one wave per (b, allele) pair; NPAIR consecutive pairs per wave
    const float bp    = *bpred;
    const int   gw    = blockIdx.x * WAVES + wv;   // 0..2047
    const int   pair0 = gw * NPAIR;                // consecutive -> same b
    const int   b     = pair0 >> 4;
    const int   i0    = pair0 & (NALLELE - 1);
    const int   rowbase = b * L_TOT;
    const int   l     = lane;                      // segment position for this lane

    float wrow[K_CAND];
    #pragma unroll
    for (int k = 0; k < K_CAND; ++k)
        wrow[k] = (l < SEG_LEN) ? s_wpool[k][l] : 0.0f;
    const float ped = (l < SEG_LEN) ? s_pedot[l] : 0.0f;

    // k held by this lane after the halving reduce: k = (b0<<2)|(b1<<1)|b2
    const int kmap = ((lane & 1) << 2) | (lane & 2) | ((lane >> 2) & 1);

    #pragma unroll
    for (int pp = 0; pp < NPAIR; ++pp) {
        const int i = i0 + pp;
        int tok = 0;
        if (l < SEG_LEN) {
            const int addr = (l < COMMON) ? (rowbase + l)
                                          : (rowbase + COMMON + 34 * i + (l - COMMON));
            tok = x[addr];
        }
        const int   tok0 = __shfl(tok, COMMON);    // presence token (lane 25)
        const float s    = (tok != 0) ? (s_edot[tok] + ped) : 0.0f;

        float p[K_CAND];
        #pragma unroll
        for (int k = 0; k < K_CAND; ++k) p[k] = wrow[k] * s;

        // halving butterfly: 8 accumulators x 64 lanes -> each lane holds S_kmap
        float q[4];
        #pragma unroll
        for (int jj = 0; jj < 4; ++jj) {
            const float tlo = __shfl_xor(p[jj],     1);
            const float thi = __shfl_xor(p[jj + 4], 1);
            q[jj] = (lane & 1) ? (p[jj + 4] + thi) : (p[jj] + tlo);
        }
        float r2[2];
        #pragma unroll
        for (int jj = 0; jj < 2; ++jj) {
            const float tlo = __shfl_xor(q[jj],     2);
            const float thi = __shfl_xor(q[jj + 2], 2);
            r2[jj] = (lane & 2) ? (q[jj + 2] + thi) : (q[jj] + tlo);
        }
        float v;
        {
            const float t0 = __shfl_xor(r2[0], 4);
            const float t1 = __shfl_xor(r2[1], 4);
            v = (lane & 4) ? (r2[1] + t1) : (r2[0] + t0);
        }
        v += __shfl_xor(v, 8);
        v += __shfl_xor(v, 16);
        v += __shfl_xor(v, 32);
        v += bp;

        // argmax over the 8 k's (first-occurrence tie-break: smaller k wins)
        float bv = v; int bk = kmap;
        #pragma unroll
        for (int m = 1; m <= 4; m <<= 1) {
            const float ov = __shfl_xor(bv, m);
            const int   ok = __shfl_xor(bk, m);
            if (ov > bv || (ov == bv && ok < bk)) { bv = ov; bk = ok; }
        }

        if (lane == 0) {
            const bool pres = (tok0 != 0);
            out[b * 32 + i]           = pres ? bv        : NEG_FILL;
            out[b * 32 + NALLELE + i] = pres ? (float)bk : -1.0f;
        }
    }
}

extern "C" void kernel_launch(void* const* d_in, const int* in_sizes, int n_in,
                              void* d_out, int out_size, void* d_ws, size_t ws_size,
                              hipStream_t stream) {
    const int*   x     = (const int*)  d_in[0];
    const float* emb   = (const float*)d_in[1];
    const float* wpool = (const float*)d_in[2];
    const float* wpred = (const float*)d_in[3];
    const float* bpred = (const float*)d_in[4];
    float*       out   = (float*)d_out;

    // 8192 pairs / (4 waves * 4 pairs) = 512 blocks
    mhc_pool_kernel<<<512, 256, 0, stream>>>(x, emb, wpool, wpred, bpred, out);
}

// Round 3
// 11.921 us; speedup vs baseline: 3.1428x; 1.5027x over previous
//
#include <hip/hip_runtime.h>

#define BATCH    512
#define L_TOT    569
#define NALLELE  16
#define SEG_LEN  59
#define D_MODEL  256
#define K_CAND   8
#define VOCAB    30
#define COMMON   25
#define NEG_FILL -1000.0f

__global__ __launch_bounds__(256) void mhc_pool_kernel(
    const int*   __restrict__ x,      // (512, 569)
    const float* __restrict__ emb,    // (30, 256)
    const float* __restrict__ wpool,  // (8, 59)
    const float* __restrict__ wpred,  // (256,)
    const float* __restrict__ bpred,  // (1,)
    float*       __restrict__ out)    // (512, 32)
{
    __shared__ float s_pa[60];          // emb half-row partials
    __shared__ float s_pb[236];         // PE quarter-row partials
    __shared__ float s_edot[VOCAB];
    __shared__ float s_pedot[SEG_LEN];
    __shared__ float s_combo[60][32];   // [l][tok], stride 32 = conflict-free gather; row 59 = zeros
    __shared__ float s_wpT[60][8];      // wpool transposed, b128-readable

    const int   t  = threadIdx.x;
    const float c0 = -0.035977892f;     // -ln(10000)/256

    // ---- step 1: thread-parallel partial dot products (no shuffles)
    if (t < 60) {                       // emb: t = 2j+h, 128 dims per thread
        const int j = t >> 1, h = t & 1;
        const float4* e = reinterpret_cast<const float4*>(emb + j * D_MODEL + h * 128);
        const float4* w = reinterpret_cast<const float4*>(wpred + h * 128);
        float a0 = 0, a1 = 0, a2 = 0, a3 = 0;
        #pragma unroll 8
        for (int q = 0; q < 32; ++q) {
            const float4 ev = e[q], wv = w[q];
            a0 = fmaf(ev.x, wv.x, a0);
            a1 = fmaf(ev.y, wv.y, a1);
            a2 = fmaf(ev.z, wv.z, a2);
            a3 = fmaf(ev.w, wv.w, a3);
        }
        s_pa[t] = (a0 + a1) + (a2 + a3);
    }
    if (t < 236) {                      // PE: t = 4j+q, 32 (sin,cos) pairs per thread
        const int   j  = t >> 2, q = t & 3;
        const float pos = (float)j;
        const int   p0  = q * 32;
        float       dv  = __expf(c0 * (float)(2 * p0));  // freq of pair p0
        const float r   = __expf(c0 * 2.0f);             // geometric ratio
        float a0 = 0.0f, a1 = 0.0f;
        #pragma unroll 8
        for (int p = 0; p < 32; ++p) {
            const float2 wv  = reinterpret_cast<const float2*>(wpred)[p0 + p];
            const float  ang = pos * dv;
            a0 = fmaf(__sinf(ang), wv.x, a0);
            a1 = fmaf(__cosf(ang), wv.y, a1);
            dv *= r;
        }
        s_pb[t] = a0 + a1;
    }
    for (int idx = t; idx < K_CAND * SEG_LEN; idx += 256) {  // wpool -> [l][k]
        const int l = idx >> 3, k = idx & 7;
        s_wpT[l][k] = wpool[k * SEG_LEN + l];
    }
    if (t < 8) s_wpT[59][t] = 0.0f;     // pad row
    __syncthreads();

    // ---- step 2: combine partials
    if (t < VOCAB) s_edot[t] = s_pa[2 * t] + s_pa[2 * t + 1];
    if (t >= 64 && t < 64 + SEG_LEN) {
        const int l = t - 64;
        s_pedot[l] = (s_pb[4 * l] + s_pb[4 * l + 1]) + (s_pb[4 * l + 2] + s_pb[4 * l + 3]);
    }
    __syncthreads();

    // ---- step 3: fused mask+score table  s_combo[l][tok]
    for (int idx = t; idx < 60 * 32; idx += 256) {
        const int l = idx >> 5, v = idx & 31;
        float s = 0.0f;
        if (l < SEG_LEN && v >= 1 && v < VOCAB) s = s_edot[v] + s_pedot[l];
        s_combo[l][v] = s;
    }
    __syncthreads();

    // ---- main: 2 threads per (b,allele) pair, 30 positions each, no gathers
    //      beyond the conflict-free combo lookup; single shfl combine.
    const float bp   = bpred[0];
    const int   g    = blockIdx.x * 256 + t;   // 0..16383
    const int   h    = g & 1;
    const int   pair = g >> 1;                 // 0..8191
    const int   i    = pair & (NALLELE - 1);
    const int   b    = pair >> 4;
    const int   rowbase = b * L_TOT;
    const int   l0   = h * 30;                 // h=0: l 0..29, h=1: l 30..59 (59 = zero pad)

    float acc[K_CAND] = {0, 0, 0, 0, 0, 0, 0, 0};
    int   tokp = 0;                            // presence token (l == 25, h == 0 only)

    #pragma unroll
    for (int q = 0; q < 30; ++q) {
        const int l = l0 + q;
        int addr;
        if (l < COMMON)       addr = rowbase + l;
        else if (l < SEG_LEN) addr = rowbase + 34 * i + l;   // 25 + 34*i + (l-25)
        else                  addr = rowbase;                // dummy, scores 0
        const int tok = x[addr];
        if (l0 == 0 && q == COMMON) tokp = tok;
        const float  s   = s_combo[l][tok];
        const float4 wlo = *reinterpret_cast<const float4*>(&s_wpT[l][0]);
        const float4 whi = *reinterpret_cast<const float4*>(&s_wpT[l][4]);
        acc[0] = fmaf(wlo.x, s, acc[0]);
        acc[1] = fmaf(wlo.y, s, acc[1]);
        acc[2] = fmaf(wlo.z, s, acc[2]);
        acc[3] = fmaf(wlo.w, s, acc[3]);
        acc[4] = fmaf(whi.x, s, acc[4]);
        acc[5] = fmaf(whi.y, s, acc[5]);
        acc[6] = fmaf(whi.z, s, acc[6]);
        acc[7] = fmaf(whi.w, s, acc[7]);
    }

    #pragma unroll
    for (int k = 0; k < K_CAND; ++k) acc[k] += __shfl_xor(acc[k], 1);

    float bv = acc[0] + bp; int bk = 0;
    #pragma unroll
    for (int k = 1; k < K_CAND; ++k) {
        const float v = acc[k] + bp;
        if (v > bv) { bv = v; bk = k; }        // strict > = first-occurrence tie-break
    }

    if (h == 0) {
        const bool pres = (tokp != 0);
        out[b * 32 + i]           = pres ? bv        : NEG_FILL;
        out[b * 32 + NALLELE + i] = pres ? (float)bk : -1.0f;
    }
}

extern "C" void kernel_launch(void* const* d_in, const int* in_sizes, int n_in,
                              void* d_out, int out_size, void* d_ws, size_t ws_size,
                              hipStream_t stream) {
    const int*   x     = (const int*)  d_in[0];
    const float* emb   = (const float*)d_in[1];
    const float* wpool = (const float*)d_in[2];
    const float* wpred = (const float*)d_in[3];
    const float* bpred = (const float*)d_in[4];
    float*       out   = (float*)d_out;

    // 8192 pairs x 2 threads = 16384 threads = 64 blocks
    mhc_pool_kernel<<<64, 256, 0, stream>>>(x, emb, wpool, wpred, bpred, out);
}

// Round 4
// 10.904 us; speedup vs baseline: 3.4360x; 1.0933x over previous
//
#include <hip/hip_runtime.h>

#define BATCH    512
#define L_TOT    569
#define NALLELE  16
#define SEG_LEN  59
#define D_MODEL  256
#define K_CAND   8
#define VOCAB    30
#define COMMON   25
#define NEG_FILL -1000.0f

// 4 threads per (b,allele) pair; thread h handles l = 15h .. 15h+14 (l=59 is a
// zero pad: s_wpT[59][*] = 0). Single __syncthreads() in the whole kernel.
__global__ __launch_bounds__(256) void mhc_pool_kernel(
    const int*   __restrict__ x,      // (512, 569)
    const float* __restrict__ emb,    // (30, 256)
    const float* __restrict__ wpool,  // (8, 59)
    const float* __restrict__ wpred,  // (256,)
    const float* __restrict__ bpred,  // (1,)
    float*       __restrict__ out)    // (512, 32)
{
    __shared__ float s_edot[VOCAB];     // <emb[v,:], wpred>
    __shared__ float s_pedot[60];       // <PE[l,:],  wpred>, [59] = 0
    __shared__ float s_wpT[60][8];      // wpool^T, row 59 = 0

    const int t = threadIdx.x;
    const int h = t & 3;                // position-slice within the pair
    const int g = blockIdx.x * 64 + (t >> 2);   // pair id 0..8191
    const int i = g & (NALLELE - 1);
    const int b = g >> 4;
    const int rowbase = b * L_TOT;

    // ---- issue all token loads FIRST; latency hides under the table build.
    int toks[15];
    #pragma unroll
    for (int q = 0; q < 15; ++q) {
        const int l = 15 * h + q;
        const int addr = (l < COMMON) ? (rowbase + l)
                       : (l < SEG_LEN) ? (rowbase + 34 * i + l)
                                       : rowbase;            // l==59 dummy
        toks[q] = x[addr];
    }
    const int tok0 = (h == 0) ? x[rowbase + COMMON + 34 * i] : 0;  // presence

    // ---- table build, no intermediate syncs (shuffle-combined partials).
    const float c0 = -0.035977892f;     // -ln(10000)/256
    if (t < 120) {                      // e_dot: quad (4 threads) per emb row
        const int j = t >> 2, q = t & 3;
        const float4* e = reinterpret_cast<const float4*>(emb + j * D_MODEL + q * 64);
        const float4* w = reinterpret_cast<const float4*>(wpred + q * 64);
        float a0 = 0, a1 = 0, a2 = 0, a3 = 0;
        #pragma unroll
        for (int p = 0; p < 16; ++p) {
            const float4 ev = e[p], wv = w[p];
            a0 = fmaf(ev.x, wv.x, a0);
            a1 = fmaf(ev.y, wv.y, a1);
            a2 = fmaf(ev.z, wv.z, a2);
            a3 = fmaf(ev.w, wv.w, a3);
        }
        float part = (a0 + a1) + (a2 + a3);
        part += __shfl_xor(part, 1);
        part += __shfl_xor(part, 2);
        if (q == 0) s_edot[j] = part;
    } else if (t < 238) {               // pe_dot: 2 threads per PE row
        const int tt = t - 120;
        const int j = tt >> 1, q = tt & 1;
        const float pos = (float)j;
        float       dv  = q ? __expf(c0 * 64.0f) : 1.0f;   // freq of pair 32q
        const float r   = __expf(c0 * 2.0f);
        float a0 = 0.0f, a1 = 0.0f;
        #pragma unroll
        for (int p = 0; p < 32; ++p) {
            const float2 wv  = reinterpret_cast<const float2*>(wpred)[32 * q + p];
            const float  ang = pos * dv;
            a0 = fmaf(__sinf(ang), wv.x, a0);
            a1 = fmaf(__cosf(ang), wv.y, a1);
            dv *= r;
        }
        float part = a0 + a1;
        part += __shfl_xor(part, 1);
        if (q == 0) s_pedot[j] = part;
        if (tt == 116) s_pedot[59] = 0.0f;   // pad (thread 236's spare slot is free)
    }
    for (int idx = t; idx < 480; idx += 256) {   // wpool^T + zero pad row
        const int l = idx >> 3, k = idx & 7;
        s_wpT[l][k] = (l < SEG_LEN) ? wpool[k * SEG_LEN + l] : 0.0f;
    }
    __syncthreads();

    // ---- main: 15 positions per thread, 8 FMA each.
    float acc[K_CAND] = {0, 0, 0, 0, 0, 0, 0, 0};
    #pragma unroll
    for (int q = 0; q < 15; ++q) {
        const int   l   = 15 * h + q;
        const int   tok = toks[q];
        const float s   = (tok != 0) ? (s_edot[tok] + s_pedot[l]) : 0.0f;
        const float4 wlo = *reinterpret_cast<const float4*>(&s_wpT[l][0]);
        const float4 whi = *reinterpret_cast<const float4*>(&s_wpT[l][4]);
        acc[0] = fmaf(wlo.x, s, acc[0]);
        acc[1] = fmaf(wlo.y, s, acc[1]);
        acc[2] = fmaf(wlo.z, s, acc[2]);
        acc[3] = fmaf(wlo.w, s, acc[3]);
        acc[4] = fmaf(whi.x, s, acc[4]);
        acc[5] = fmaf(whi.y, s, acc[5]);
        acc[6] = fmaf(whi.z, s, acc[6]);
        acc[7] = fmaf(whi.w, s, acc[7]);
    }

    // reduce across the 4 threads of the pair
    #pragma unroll
    for (int k = 0; k < K_CAND; ++k) {
        acc[k] += __shfl_xor(acc[k], 1);
        acc[k] += __shfl_xor(acc[k], 2);
    }

    if (h == 0) {
        float bv = acc[0]; int bk = 0;
        #pragma unroll
        for (int k = 1; k < K_CAND; ++k)
            if (acc[k] > bv) { bv = acc[k]; bk = k; }   // strict >: first-occurrence
        const bool pres = (tok0 != 0);
        out[b * 32 + i]           = pres ? (bv + bpred[0]) : NEG_FILL;
        out[b * 32 + NALLELE + i] = pres ? (float)bk       : -1.0f;
    }
}

extern "C" void kernel_launch(void* const* d_in, const int* in_sizes, int n_in,
                              void* d_out, int out_size, void* d_ws, size_t ws_size,
                              hipStream_t stream) {
    const int*   x     = (const int*)  d_in[0];
    const float* emb   = (const float*)d_in[1];
    const float* wpool = (const float*)d_in[2];
    const float* wpred = (const float*)d_in[3];
    const float* bpred = (const float*)d_in[4];
    float*       out   = (float*)d_out;

    // 8192 pairs x 4 threads = 32768 threads = 128 blocks
    mhc_pool_kernel<<<128, 256, 0, stream>>>(x, emb, wpool, wpred, bpred, out);
}